// Round 12
// baseline (226.240 us; speedup 1.0000x reference)
//
#include <hip/hip_runtime.h>
#include <hip/hip_bf16.h>

// TurnGPT attention block: y = proj(softmax(causal(QK^T/8)) V), qkv = x@W_attn+b
// B=2, T=2048, C=1024, H=16, D=64. d_in/d_out are FP32; bf16 MFMA inside.
//
// LDS swizzle: glds16 can only write lane-linear images, so instead of padding
// we XOR-swizzle the 16B chunk index with ((row%16)>>1)&3 by permuting the
// GLOBAL source column per lane. Readers apply the same XOR -> 2-way banks.

typedef __bf16 bf16_t;
typedef __bf16 bf16x8 __attribute__((ext_vector_type(8)));
typedef float f32x4 __attribute__((ext_vector_type(4)));
typedef unsigned short ushort_t;

#define LOG2E 1.44269504088896340736f

__device__ __forceinline__ void glds16(const bf16_t* g, ushort_t* l) {
  __builtin_amdgcn_global_load_lds(
      (const __attribute__((address_space(1))) unsigned int*)g,
      (__attribute__((address_space(3))) unsigned int*)l, 16, 0, 0);
}

// ---------------- fused prep: cvt(x) + transpose_cvt(W_attn) + (W_proj) ------
__global__ __launch_bounds__(256) void prep_kernel(
    const float* __restrict__ x, const float* __restrict__ W_attn,
    const float* __restrict__ W_proj, ushort_t* __restrict__ Xb,
    ushort_t* __restrict__ WtA, ushort_t* __restrict__ WtP) {
  const int bid = blockIdx.x, tid = threadIdx.x;
  if (bid < 4096) {                      // cvt: x fp32 -> bf16, 4 elems/thread
    int i = bid * 256 + tid;
    float4 v = ((const float4*)x)[i];
    ushort4 o;
    o.x = __builtin_bit_cast(unsigned short, (bf16_t)v.x);
    o.y = __builtin_bit_cast(unsigned short, (bf16_t)v.y);
    o.z = __builtin_bit_cast(unsigned short, (bf16_t)v.z);
    o.w = __builtin_bit_cast(unsigned short, (bf16_t)v.w);
    ((ushort4*)Xb)[i] = o;
    return;
  }
  __shared__ ushort_t tile[32][33];
  const float* in;
  ushort_t* out;
  int C, bx, by;
  if (bid < 4096 + 3072) { int idx = bid - 4096; in = W_attn; out = WtA; C = 3072; bx = idx % 96; by = idx / 96; }
  else                   { int idx = bid - 7168; in = W_proj; out = WtP; C = 1024; bx = idx % 32; by = idx / 32; }
  const int tx = tid & 31, ty = tid >> 5;
  int cbase = bx * 32, rbase = by * 32;
#pragma unroll
  for (int i = ty; i < 32; i += 8)
    tile[i][tx] = __builtin_bit_cast(
        unsigned short, (bf16_t)in[(size_t)(rbase + i) * C + cbase + tx]);
  __syncthreads();
#pragma unroll
  for (int i = ty; i < 32; i += 8)
    out[(size_t)(cbase + i) * 1024 + rbase + tx] = tile[tx][i];
}

// ---------------- shared 128x128 GEMM mainloop (single-buf + swizzled LDS) ---
__device__ __forceinline__ void gemm128_mainloop(
    const bf16_t* __restrict__ A, const bf16_t* __restrict__ Bt, int K,
    int mtile, int ntile, ushort_t* As, ushort_t* Bs, f32x4 acc[4][4]) {
  const int tid  = threadIdx.x;
  const int lane = tid & 63, wave = tid >> 6;
  const int l15  = lane & 15, quad = lane >> 4;
  const int wrow = (wave >> 1) * 64, wcol = (wave & 1) * 64;
  const int lr = lane >> 2;                        // row within 16-row group
  const int lc = (((lane & 3) ^ ((lr >> 1) & 3)) * 8);  // swizzled src col
  const bf16_t* Ap = A + (size_t)(mtile + wave * 32 + lr) * K + lc;
  const bf16_t* Bp = Bt + (size_t)(ntile + wave * 32 + lr) * K + lc;
  const int rsw = (quad ^ ((l15 >> 1) & 3)) * 8;   // swizzled read chunk
  ushort_t* Asw = As + wave * 32 * 32;
  ushort_t* Bsw = Bs + wave * 32 * 32;
  for (int kb = 0; kb < K; kb += 32) {
    __syncthreads();                    // prior iter's LDS reads done
#pragma unroll
    for (int c = 0; c < 2; c++) {       // 16 rows per call (64 lanes x 16B)
      glds16(Ap + (size_t)(c * 16) * K + kb, Asw + c * 16 * 32);
      glds16(Bp + (size_t)(c * 16) * K + kb, Bsw + c * 16 * 32);
    }
    __syncthreads();                    // drains vmcnt -> staged data visible
    bf16x8 af[4], bfr[4];
#pragma unroll
    for (int i = 0; i < 4; i++)
      af[i] = *(const bf16x8*)&As[(wrow + i * 16 + l15) * 32 + rsw];
#pragma unroll
    for (int j = 0; j < 4; j++)
      bfr[j] = *(const bf16x8*)&Bs[(wcol + j * 16 + l15) * 32 + rsw];
#pragma unroll
    for (int i = 0; i < 4; i++)
#pragma unroll
      for (int j = 0; j < 4; j++)
        acc[i][j] = __builtin_amdgcn_mfma_f32_16x16x32_bf16(af[i], bfr[j], acc[i][j], 0, 0, 0);
  }
}

// ---------------- QKV GEMM: Xb[4096,1024] @ W_attn + b ----------------
// epilogue: Q,K -> [B*H][T][D] coalesced; V -> Vt[B*H][D][T] direct scatter
// (2B stores, L2 write-combined; measured faster than a separate transpose).
__global__ __launch_bounds__(256) void qkv_gemm_kernel(
    const bf16_t* __restrict__ X, const bf16_t* __restrict__ WtA,
    const float* __restrict__ bias, bf16_t* __restrict__ Qd,
    bf16_t* __restrict__ Kd, bf16_t* __restrict__ Vtd) {
  __shared__ ushort_t As[128 * 32];
  __shared__ ushort_t Bs[128 * 32];
  const int mtile = blockIdx.x * 128, ntile = blockIdx.y * 128;
  f32x4 acc[4][4] = {};
  gemm128_mainloop(X, WtA, 1024, mtile, ntile, As, Bs, acc);
  const int tid = threadIdx.x, lane = tid & 63, wave = tid >> 6;
  const int l15 = lane & 15, quad = lane >> 4;
  const int wrow = (wave >> 1) * 64, wcol = (wave & 1) * 64;
#pragma unroll
  for (int j = 0; j < 4; j++) {
    int n = ntile + wcol + j * 16 + l15;           // [0,3072)
    float bv = bias[n];
    int sec = n >> 10, cc = n & 1023, h = cc >> 6, d = cc & 63;
#pragma unroll
    for (int i = 0; i < 4; i++) {
#pragma unroll
      for (int r = 0; r < 4; r++) {
        int m = mtile + wrow + i * 16 + quad * 4 + r;   // [0,4096)
        int b = m >> 11, t = m & 2047;
        size_t bh = (size_t)(b * 16 + h);
        bf16_t v = (bf16_t)(acc[i][j][r] + bv);
        if (sec == 0)      Qd[(bh * 2048 + t) * 64 + d] = v;
        else if (sec == 1) Kd[(bh * 2048 + t) * 64 + d] = v;
        else               Vtd[(bh * 64 + d) * 2048 + t] = v;
      }
    }
  }
}

// ---------------- flash attention (4 waves, 64-row q-tile, TK=32) ------------
// Grid 32 qt x 32 bh = 1024 blocks -> 4 blocks/CU: 4 independent barrier
// domains per CU (vs 2 in the 512-thr version) = the latency-hiding that the
// 8-wave block could not provide. LDS ~21 KB, single P buffer, swizzled.
__global__ __launch_bounds__(256) void attn_kernel(
    const bf16_t* __restrict__ Q, const bf16_t* __restrict__ K,
    const bf16_t* __restrict__ Vt, bf16_t* __restrict__ Y) {
  __shared__ ushort_t Ks[2][2048];       // [buf][kc*1024 + t*32 + chunk]
  __shared__ ushort_t Vs[2][2048];       // [buf][d*32 + chunk]
  __shared__ ushort_t Ps[4][16 * 40];    // per-wave P [16 q][32 k], pad 40
  const int bh = blockIdx.y;
  const int qt = 31 - (int)blockIdx.x;   // big blocks dispatch first
  const int tid = threadIdx.x, wave = tid >> 6, lane = tid & 63;
  const int l15 = lane & 15, quad = lane >> 4;
  const bf16_t* Qh = Q + (size_t)bh * 2048 * 64;
  const bf16_t* Kh = K + (size_t)bh * 2048 * 64;
  const bf16_t* Vh = Vt + (size_t)bh * 64 * 2048;
  const int b = bh >> 4, h = bh & 15;
  const float SC = 0.125f * LOG2E;
  const int qw = qt * 64 + wave * 16;    // wave's q-row base
  const int nkt = 2 * qt + 2;            // 32-wide k-tiles (covers qt*64+63)

  bf16x8 qa[2];
#pragma unroll
  for (int kc = 0; kc < 2; kc++)
    qa[kc] = *(const bf16x8*)(Qh + (size_t)(qw + l15) * 64 + kc * 32 + quad * 8);

  f32x4 o[4] = {};
  float lpart[4] = {};
  const int rsw = (quad ^ ((l15 >> 1) & 3)) * 8;   // swizzled read chunk

  // staging: waves 0-1 -> K (wave w: plane c rows w*16+[0,16), 2 glds),
  //          waves 2-3 -> V (wave w-2: d rows (w-2)*32+c*16+[0,16), 2 glds)
  const int lr4 = lane >> 2;
  const int csw = ((lane & 3) ^ ((lr4 >> 1) & 3)) * 8;
  const bool isK = wave < 2;
  const int sw = isK ? wave : wave - 2;
  const bf16_t* gp0;     // source for c=0 chunk; c=1 adds coff
  size_t coff, rowstep, kstep;
  ushort_t *dst0, *dst1;
  int dstep;
  if (isK) {   // K[t][d]: rows t = sw*16+lr4, col = c*32 + csw
    gp0 = Kh + (size_t)(sw * 16 + lr4) * 64 + csw;
    coff = 32;                       // next kc plane: col += 32
    rowstep = 0;                     // (rows advance only via kt)
    kstep = (size_t)32 * 64;
    dst0 = Ks[0] + sw * 16 * 32;  dst1 = Ks[1] + sw * 16 * 32;
    dstep = 1024;                    // next plane in LDS
  } else {     // Vt[d][t]: rows d = sw*32 + c*16 + lr4, col = kt*32 + csw
    gp0 = Vh + (size_t)(sw * 32 + lr4) * 2048 + csw;
    coff = (size_t)16 * 2048;        // next 16 d-rows
    rowstep = 0;
    kstep = 32;
    dst0 = Vs[0] + sw * 32 * 32;  dst1 = Vs[1] + sw * 32 * 32;
    dstep = 512;                     // next 16 rows in LDS
  }

#pragma unroll
  for (int c = 0; c < 2; c++)          // prologue: tile 0 -> buf 0
    glds16(gp0 + (size_t)c * coff, dst0 + c * dstep);

  f32x4 zz = {0.f, 0.f, 0.f, 0.f};
  for (int kt = 0; kt < nkt; kt++) {
    const int cur = kt & 1;
    __syncthreads();                   // cur buf visible
    if (kt + 1 < nkt) {
      ushort_t* nd = cur ? dst0 : dst1;
#pragma unroll
      for (int c = 0; c < 2; c++)
        glds16(gp0 + (size_t)(kt + 1) * kstep + (size_t)c * coff, nd + c * dstep);
    }
    const int kb32 = kt * 32;
    if (kb32 <= qw + 15) {             // wave-uniform skip of masked tiles
      bf16x8 kb[2][2];
#pragma unroll
      for (int bn = 0; bn < 2; bn++)
#pragma unroll
        for (int kc = 0; kc < 2; kc++)
          kb[bn][kc] = *(const bf16x8*)&Ks[cur][kc * 1024 + (bn * 16 + l15) * 32 + rsw];
      f32x4 s[2];
#pragma unroll
      for (int bn = 0; bn < 2; bn++) {
        f32x4 t0 = __builtin_amdgcn_mfma_f32_16x16x32_bf16(qa[0], kb[bn][0], zz, 0, 0, 0);
        s[bn] = __builtin_amdgcn_mfma_f32_16x16x32_bf16(qa[1], kb[bn][1], t0, 0, 0, 0);
      }
      const bool dg = (kb32 + 31 > qw);
#pragma unroll
      for (int r = 0; r < 4; r++) {
        int row = qw + quad * 4 + r;
        float v0 = s[0][r] * SC, v1 = s[1][r] * SC;
        if (dg) {
          int c0 = kb32 + l15;
          if (c0 > row) v0 = -1e5f;
          if (c0 + 16 > row) v1 = -1e5f;
        }
        float p0 = exp2f(fminf(v0, 115.0f)), p1 = exp2f(fminf(v1, 115.0f));
        lpart[r] += p0 + p1;
        int prow = (quad * 4 + r) * 40;
        Ps[wave][prow + l15]      = __builtin_bit_cast(unsigned short, (bf16_t)p0);
        Ps[wave][prow + 16 + l15] = __builtin_bit_cast(unsigned short, (bf16_t)p1);
      }
      __asm__ volatile("s_waitcnt lgkmcnt(0)" ::: "memory");
      bf16x8 pa, vb[4];
      pa = *(const bf16x8*)&Ps[wave][l15 * 40 + quad * 8];
#pragma unroll
      for (int ns = 0; ns < 4; ns++)
        vb[ns] = *(const bf16x8*)&Vs[cur][(ns * 16 + l15) * 32 + rsw];
#pragma unroll
      for (int ns = 0; ns < 4; ns++)
        o[ns] = __builtin_amdgcn_mfma_f32_16x16x32_bf16(pa, vb[ns], o[ns], 0, 0, 0);
    }
  }
  // epilogue: reduce l across the 16-lane row group, then y = o / l
#pragma unroll
  for (int r = 0; r < 4; r++) {
    float l = lpart[r];
#pragma unroll
    for (int off = 1; off < 16; off <<= 1) l += __shfl_xor(l, off);
    float inv_l = 1.0f / fmaxf(l, 1e-30f);
    int t = qw + quad * 4 + r;
#pragma unroll
    for (int ns = 0; ns < 4; ns++) {
      int c = h * 64 + ns * 16 + l15;
      Y[((size_t)(b * 2048 + t)) * 1024 + c] = (bf16_t)(o[ns][r] * inv_l);
    }
  }
}

// ---------------- proj GEMM: Yb[4096,1024] @ W_proj + b -> FP32 out ----------
__global__ __launch_bounds__(256) void proj_gemm_kernel(
    const bf16_t* __restrict__ Yb, const bf16_t* __restrict__ WtP,
    const float* __restrict__ bias, float* __restrict__ out) {
  __shared__ ushort_t As[128 * 32];
  __shared__ ushort_t Bs[128 * 32];
  const int mtile = blockIdx.x * 128, ntile = blockIdx.y * 128;
  f32x4 acc[4][4] = {};
  gemm128_mainloop(Yb, WtP, 1024, mtile, ntile, As, Bs, acc);
  const int tid = threadIdx.x, lane = tid & 63, wave = tid >> 6;
  const int l15 = lane & 15, quad = lane >> 4;
  const int wrow = (wave >> 1) * 64, wcol = (wave & 1) * 64;
#pragma unroll
  for (int j = 0; j < 4; j++) {
    int n = ntile + wcol + j * 16 + l15;
    float bv = bias[n];
#pragma unroll
    for (int i = 0; i < 4; i++) {
#pragma unroll
      for (int r = 0; r < 4; r++) {
        int m = mtile + wrow + i * 16 + quad * 4 + r;
        out[(size_t)m * 1024 + n] = acc[i][j][r] + bv;
      }
    }
  }
}

extern "C" void kernel_launch(void* const* d_in, const int* in_sizes, int n_in,
                              void* d_out, int out_size, void* d_ws, size_t ws_size,
                              hipStream_t stream) {
  const float* x      = (const float*)d_in[0];   // [2,2048,1024]
  const float* W_attn = (const float*)d_in[1];   // [1024,3072]
  const float* b_attn = (const float*)d_in[2];   // [3072]
  const float* W_proj = (const float*)d_in[3];   // [1024,1024]
  const float* b_proj = (const float*)d_in[4];   // [1024]
  float* out = (float*)d_out;                    // [2,2048,1024]

  bf16_t* ws  = (bf16_t*)d_ws;
  bf16_t* WtA = ws;                                // 3072*1024
  bf16_t* WtP = WtA + (size_t)3072 * 1024;         // 1024*1024
  bf16_t* Xb  = WtP + (size_t)1024 * 1024;         // 4096*1024
  bf16_t* Qb  = Xb + (size_t)4194304;
  bf16_t* Kb  = Qb + (size_t)4194304;
  bf16_t* Vtb = Kb + (size_t)4194304;
  bf16_t* Yb  = Vtb + (size_t)4194304;             // ~48 MB bf16 total

  prep_kernel<<<8192, 256, 0, stream>>>(x, W_attn, W_proj,
      (ushort_t*)Xb, (ushort_t*)WtA, (ushort_t*)WtP);
  qkv_gemm_kernel<<<dim3(32, 24), 256, 0, stream>>>(Xb, WtA, b_attn, Qb, Kb, Vtb);
  attn_kernel<<<dim3(32, 32), 256, 0, stream>>>(Qb, Kb, Vtb, Yb);
  proj_gemm_kernel<<<dim3(32, 8), 256, 0, stream>>>(Yb, WtP, b_proj, out);
}

// Round 13
// 217.471 us; speedup vs baseline: 1.0403x; 1.0403x over previous
//
#include <hip/hip_runtime.h>
#include <hip/hip_bf16.h>

// TurnGPT attention block: y = proj(softmax(causal(QK^T/8)) V), qkv = x@W_attn+b
// B=2, T=2048, C=1024, H=16, D=64. d_in/d_out are FP32; bf16 MFMA inside.

typedef __bf16 bf16_t;
typedef __bf16 bf16x8 __attribute__((ext_vector_type(8)));
typedef float f32x4 __attribute__((ext_vector_type(4)));
typedef unsigned short ushort_t;

#define LOG2E 1.44269504088896340736f

__device__ __forceinline__ void glds16(const bf16_t* g, ushort_t* l) {
  __builtin_amdgcn_global_load_lds(
      (const __attribute__((address_space(1))) unsigned int*)g,
      (__attribute__((address_space(3))) unsigned int*)l, 16, 0, 0);
}

// ---------------- fused prep: cvt(x) + transpose_cvt(W_attn) + (W_proj) ------
__global__ __launch_bounds__(256) void prep_kernel(
    const float* __restrict__ x, const float* __restrict__ W_attn,
    const float* __restrict__ W_proj, ushort_t* __restrict__ Xb,
    ushort_t* __restrict__ WtA, ushort_t* __restrict__ WtP) {
  const int bid = blockIdx.x, tid = threadIdx.x;
  if (bid < 4096) {
    int i = bid * 256 + tid;
    float4 v = ((const float4*)x)[i];
    ushort4 o;
    o.x = __builtin_bit_cast(unsigned short, (bf16_t)v.x);
    o.y = __builtin_bit_cast(unsigned short, (bf16_t)v.y);
    o.z = __builtin_bit_cast(unsigned short, (bf16_t)v.z);
    o.w = __builtin_bit_cast(unsigned short, (bf16_t)v.w);
    ((ushort4*)Xb)[i] = o;
    return;
  }
  __shared__ ushort_t tile[32][33];
  const float* in;
  ushort_t* out;
  int C, bx, by;
  if (bid < 4096 + 3072) { int idx = bid - 4096; in = W_attn; out = WtA; C = 3072; bx = idx % 96; by = idx / 96; }
  else                   { int idx = bid - 7168; in = W_proj; out = WtP; C = 1024; bx = idx % 32; by = idx / 32; }
  const int tx = tid & 31, ty = tid >> 5;
  int cbase = bx * 32, rbase = by * 32;
#pragma unroll
  for (int i = ty; i < 32; i += 8)
    tile[i][tx] = __builtin_bit_cast(
        unsigned short, (bf16_t)in[(size_t)(rbase + i) * C + cbase + tx]);
  __syncthreads();
#pragma unroll
  for (int i = ty; i < 32; i += 8)
    out[(size_t)(cbase + i) * 1024 + rbase + tx] = tile[tx][i];
}

// ---------------- shared 128x128 GEMM mainloop (BK=64, swizzled LDS) ---------
// LDS [128][64] ushort per matrix (16 KB). Image: LDS[r][ch] holds source
// chunk ch^(r&7) (8 chunks of 16B per row). Stager lane: row lane>>3, chunk
// lane&7 -> source col ((lane&7)^(row&7))*8. Reader wants chunk cc=s*4+quad
// -> reads ch = cc^(r&7). Banks: 8 groups x 2 lanes = 2-way (free).
__device__ __forceinline__ void gemm128_mainloop(
    const bf16_t* __restrict__ A, const bf16_t* __restrict__ Bt, int K,
    int mtile, int ntile, ushort_t* As, ushort_t* Bs, f32x4 acc[4][4]) {
  const int tid  = threadIdx.x;
  const int lane = tid & 63, wave = tid >> 6;
  const int l15  = lane & 15, quad = lane >> 4;
  const int wrow = (wave >> 1) * 64, wcol = (wave & 1) * 64;
  const int lr8 = lane >> 3;                       // 0..7 row in 8-row group
  const int sc  = ((lane & 7) ^ lr8) * 8;          // swizzled source col
  const bf16_t* Ap = A + (size_t)(mtile + wave * 32 + lr8) * K + sc;
  const bf16_t* Bp = Bt + (size_t)(ntile + wave * 32 + lr8) * K + sc;
  ushort_t* Asw = As + wave * 32 * 64;
  ushort_t* Bsw = Bs + wave * 32 * 64;
  const int ch7 = l15 & 7;                         // reader row&7
  for (int kb = 0; kb < K; kb += 64) {
    __syncthreads();                    // prior iter's LDS reads done
#pragma unroll
    for (int c = 0; c < 4; c++) {       // 8 rows per call (64 lanes x 16B)
      glds16(Ap + (size_t)(c * 8) * K + kb, Asw + c * 8 * 64);
      glds16(Bp + (size_t)(c * 8) * K + kb, Bsw + c * 8 * 64);
    }
    __syncthreads();                    // drains vmcnt -> staged data visible
#pragma unroll
    for (int s = 0; s < 2; s++) {
      const int rch = ((s * 4 + quad) ^ ch7) * 8;
      bf16x8 af[4], bfr[4];
#pragma unroll
      for (int i = 0; i < 4; i++)
        af[i] = *(const bf16x8*)&As[(wrow + i * 16 + l15) * 64 + rch];
#pragma unroll
      for (int j = 0; j < 4; j++)
        bfr[j] = *(const bf16x8*)&Bs[(wcol + j * 16 + l15) * 64 + rch];
#pragma unroll
      for (int i = 0; i < 4; i++)
#pragma unroll
        for (int j = 0; j < 4; j++)
          acc[i][j] = __builtin_amdgcn_mfma_f32_16x16x32_bf16(af[i], bfr[j], acc[i][j], 0, 0, 0);
    }
  }
}

// ---------------- QKV GEMM: Xb[4096,1024] @ W_attn + b ----------------
__global__ __launch_bounds__(256) void qkv_gemm_kernel(
    const bf16_t* __restrict__ X, const bf16_t* __restrict__ WtA,
    const float* __restrict__ bias, bf16_t* __restrict__ Qd,
    bf16_t* __restrict__ Kd, bf16_t* __restrict__ Vtd) {
  __shared__ ushort_t As[128 * 64];
  __shared__ ushort_t Bs[128 * 64];
  const int mtile = blockIdx.x * 128, ntile = blockIdx.y * 128;
  f32x4 acc[4][4] = {};
  gemm128_mainloop(X, WtA, 1024, mtile, ntile, As, Bs, acc);
  const int tid = threadIdx.x, lane = tid & 63, wave = tid >> 6;
  const int l15 = lane & 15, quad = lane >> 4;
  const int wrow = (wave >> 1) * 64, wcol = (wave & 1) * 64;
#pragma unroll
  for (int j = 0; j < 4; j++) {
    int n = ntile + wcol + j * 16 + l15;           // [0,3072)
    float bv = bias[n];
    int sec = n >> 10, cc = n & 1023, h = cc >> 6, d = cc & 63;
#pragma unroll
    for (int i = 0; i < 4; i++) {
#pragma unroll
      for (int r = 0; r < 4; r++) {
        int m = mtile + wrow + i * 16 + quad * 4 + r;   // [0,4096)
        int b = m >> 11, t = m & 2047;
        size_t bh = (size_t)(b * 16 + h);
        bf16_t v = (bf16_t)(acc[i][j][r] + bv);
        if (sec == 0)      Qd[(bh * 2048 + t) * 64 + d] = v;
        else if (sec == 1) Kd[(bh * 2048 + t) * 64 + d] = v;
        else               Vtd[(bh * 64 + d) * 2048 + t] = v;
      }
    }
  }
}

// ---------------- flash attention (TK=64, triple-buffer, raw barrier) --------
// r10 structure + 3-deep K/V buffers. Raw s_barrier with s_waitcnt vmcnt(2)
// (vmcnt(0) only on the last tile): tile j+1's glds stays IN FLIGHT across the
// barrier -> 2-iteration prefetch distance, unlike __syncthreads which drains
// vmcnt(0) and caps prefetch at one iteration.
__global__ __launch_bounds__(512) void attn_kernel(
    const bf16_t* __restrict__ Q, const bf16_t* __restrict__ K,
    const bf16_t* __restrict__ Vt, bf16_t* __restrict__ Y) {
  __shared__ ushort_t Ks[3][4096];       // [buf][kc*2048 + t*32 + chunk]
  __shared__ ushort_t Vs[3][4096];       // [buf][tHalf*2048 + d*32 + chunk]
  __shared__ ushort_t Ps[8][16 * 40];    // per-wave P [16 q][32 k], pad 40
  const int bh = blockIdx.y;
  const int qt = 15 - (int)blockIdx.x;   // big blocks dispatch first
  const int tid = threadIdx.x, wave = tid >> 6, lane = tid & 63;
  const int l15 = lane & 15, quad = lane >> 4;
  const bf16_t* Qh = Q + (size_t)bh * 2048 * 64;
  const bf16_t* Kh = K + (size_t)bh * 2048 * 64;
  const bf16_t* Vh = Vt + (size_t)bh * 64 * 2048;
  const int b = bh >> 4, h = bh & 15;
  const float SC = 0.125f * LOG2E;
  const int qw = qt * 128 + wave * 16;   // wave's q-row base
  const int nkt = 2 * qt + 2;            // 64-wide k-tiles (>= 2)

  bf16x8 qa[2];
#pragma unroll
  for (int kc = 0; kc < 2; kc++)
    qa[kc] = *(const bf16x8*)(Qh + (size_t)(qw + l15) * 64 + kc * 32 + quad * 8);

  f32x4 o[4] = {};
  float lpart[4] = {};
  const int rsw = (quad ^ ((l15 >> 1) & 3)) * 8;   // swizzled read chunk

  // staging: waves 0-3 -> K, waves 4-7 -> V; 2 glds16/wave/tile, swizzled cols
  const int lr4 = lane >> 2;
  const int csw = ((lane & 3) ^ ((lr4 >> 1) & 3)) * 8;
  const bool isK = wave < 4;
  const int sw = isK ? wave : wave - 4;
  const int rbase = (sw & 1) * 32;
  const bf16_t* gp0;
  size_t rowstep;
  if (isK) { gp0 = Kh + (size_t)(rbase + lr4) * 64 + (sw >> 1) * 32 + csw;  rowstep = 64; }
  else     { gp0 = Vh + (size_t)(rbase + lr4) * 2048 + (sw >> 1) * 32 + csw; rowstep = 2048; }
  const size_t kstep = isK ? (size_t)64 * 64 : 64;
  ushort_t* dstB = (isK ? Ks[0] : Vs[0]) + (sw >> 1) * 2048 + rbase * 32;

  // prologue: tile 0 -> buf 0, tile 1 -> buf 1 (nkt >= 2 always)
#pragma unroll
  for (int c = 0; c < 2; c++) {
    glds16(gp0 + (size_t)(c * 16) * rowstep, dstB + c * 512);
    glds16(gp0 + kstep + (size_t)(c * 16) * rowstep, dstB + 4096 + c * 512);
  }

  f32x4 zz = {0.f, 0.f, 0.f, 0.f};
  int cur = 0, prev = 2;                 // prev == (kt+2)%3 at iter kt
  for (int kt = 0; kt < nkt; kt++) {
    // drain tile kt's loads (oldest 2); keep tile kt+1's in flight
    if (kt + 1 < nkt) __asm__ volatile("s_waitcnt vmcnt(2)" ::: "memory");
    else              __asm__ volatile("s_waitcnt vmcnt(0)" ::: "memory");
    __asm__ volatile("s_barrier" ::: "memory");
    if (kt + 2 < nkt) {                  // prefetch tile kt+2 into buf prev
      ushort_t* nd = dstB + prev * 4096;
#pragma unroll
      for (int c = 0; c < 2; c++)
        glds16(gp0 + (size_t)(kt + 2) * kstep + (size_t)(c * 16) * rowstep, nd + c * 512);
    }
    const ushort_t* KsC = Ks[0] + cur * 4096;
    const ushort_t* VsC = Vs[0] + cur * 4096;
#pragma unroll
    for (int h32 = 0; h32 < 2; h32++) {
      const int kb32 = kt * 64 + h32 * 32;
      if (kb32 > qw + 15) break;         // wave-uniform skip
      bf16x8 kb[2][2];
#pragma unroll
      for (int bn = 0; bn < 2; bn++)
#pragma unroll
        for (int kc = 0; kc < 2; kc++)
          kb[bn][kc] = *(const bf16x8*)&KsC[kc * 2048 + (h32 * 32 + bn * 16 + l15) * 32 + rsw];
      f32x4 s[2];
#pragma unroll
      for (int bn = 0; bn < 2; bn++) {
        f32x4 t0 = __builtin_amdgcn_mfma_f32_16x16x32_bf16(qa[0], kb[bn][0], zz, 0, 0, 0);
        s[bn] = __builtin_amdgcn_mfma_f32_16x16x32_bf16(qa[1], kb[bn][1], t0, 0, 0, 0);
      }
      const bool dg = (kb32 + 31 > qw);
#pragma unroll
      for (int r = 0; r < 4; r++) {
        int row = qw + quad * 4 + r;
        float v0 = s[0][r] * SC, v1 = s[1][r] * SC;
        if (dg) {
          int c0 = kb32 + l15;
          if (c0 > row) v0 = -1e5f;
          if (c0 + 16 > row) v1 = -1e5f;
        }
        float p0 = exp2f(fminf(v0, 115.0f)), p1 = exp2f(fminf(v1, 115.0f));
        lpart[r] += p0 + p1;
        int prow = (quad * 4 + r) * 40;
        Ps[wave][prow + l15]      = __builtin_bit_cast(unsigned short, (bf16_t)p0);
        Ps[wave][prow + 16 + l15] = __builtin_bit_cast(unsigned short, (bf16_t)p1);
      }
      __asm__ volatile("s_waitcnt lgkmcnt(0)" ::: "memory");
      bf16x8 pa, vb[4];
      pa = *(const bf16x8*)&Ps[wave][l15 * 40 + quad * 8];
#pragma unroll
      for (int ns = 0; ns < 4; ns++)
        vb[ns] = *(const bf16x8*)&VsC[h32 * 2048 + (ns * 16 + l15) * 32 + rsw];
#pragma unroll
      for (int ns = 0; ns < 4; ns++)
        o[ns] = __builtin_amdgcn_mfma_f32_16x16x32_bf16(pa, vb[ns], o[ns], 0, 0, 0);
    }
    prev = cur;
    cur = (cur == 2) ? 0 : cur + 1;
  }
  // epilogue: reduce l across the 16-lane row group, then y = o / l
#pragma unroll
  for (int r = 0; r < 4; r++) {
    float l = lpart[r];
#pragma unroll
    for (int off = 1; off < 16; off <<= 1) l += __shfl_xor(l, off);
    float inv_l = 1.0f / fmaxf(l, 1e-30f);
    int t = qw + quad * 4 + r;
#pragma unroll
    for (int ns = 0; ns < 4; ns++) {
      int c = h * 64 + ns * 16 + l15;
      Y[((size_t)(b * 2048 + t)) * 1024 + c] = (bf16_t)(o[ns][r] * inv_l);
    }
  }
}

// ---------------- proj GEMM: Yb[4096,1024] @ W_proj + b -> FP32 out ----------
__global__ __launch_bounds__(256) void proj_gemm_kernel(
    const bf16_t* __restrict__ Yb, const bf16_t* __restrict__ WtP,
    const float* __restrict__ bias, float* __restrict__ out) {
  __shared__ ushort_t As[128 * 64];
  __shared__ ushort_t Bs[128 * 64];
  const int mtile = blockIdx.x * 128, ntile = blockIdx.y * 128;
  f32x4 acc[4][4] = {};
  gemm128_mainloop(Yb, WtP, 1024, mtile, ntile, As, Bs, acc);
  const int tid = threadIdx.x, lane = tid & 63, wave = tid >> 6;
  const int l15 = lane & 15, quad = lane >> 4;
  const int wrow = (wave >> 1) * 64, wcol = (wave & 1) * 64;
#pragma unroll
  for (int j = 0; j < 4; j++) {
    int n = ntile + wcol + j * 16 + l15;
    float bv = bias[n];
#pragma unroll
    for (int i = 0; i < 4; i++) {
#pragma unroll
      for (int r = 0; r < 4; r++) {
        int m = mtile + wrow + i * 16 + quad * 4 + r;
        out[(size_t)m * 1024 + n] = acc[i][j][r] + bv;
      }
    }
  }
}

extern "C" void kernel_launch(void* const* d_in, const int* in_sizes, int n_in,
                              void* d_out, int out_size, void* d_ws, size_t ws_size,
                              hipStream_t stream) {
  const float* x      = (const float*)d_in[0];   // [2,2048,1024]
  const float* W_attn = (const float*)d_in[1];   // [1024,3072]
  const float* b_attn = (const float*)d_in[2];   // [3072]
  const float* W_proj = (const float*)d_in[3];   // [1024,1024]
  const float* b_proj = (const float*)d_in[4];   // [1024]
  float* out = (float*)d_out;                    // [2,2048,1024]

  bf16_t* ws  = (bf16_t*)d_ws;
  bf16_t* WtA = ws;                                // 3072*1024
  bf16_t* WtP = WtA + (size_t)3072 * 1024;         // 1024*1024
  bf16_t* Xb  = WtP + (size_t)1024 * 1024;         // 4096*1024
  bf16_t* Qb  = Xb + (size_t)4194304;
  bf16_t* Kb  = Qb + (size_t)4194304;
  bf16_t* Vtb = Kb + (size_t)4194304;
  bf16_t* Yb  = Vtb + (size_t)4194304;             // ~48 MB bf16 total

  prep_kernel<<<8192, 256, 0, stream>>>(x, W_attn, W_proj,
      (ushort_t*)Xb, (ushort_t*)WtA, (ushort_t*)WtP);
  qkv_gemm_kernel<<<dim3(32, 24), 256, 0, stream>>>(Xb, WtA, b_attn, Qb, Kb, Vtb);
  attn_kernel<<<dim3(16, 32), 512, 0, stream>>>(Qb, Kb, Vtb, Yb);
  proj_gemm_kernel<<<dim3(32, 8), 256, 0, stream>>>(Yb, WtP, b_proj, out);
}